// Round 7
// baseline (1686.495 us; speedup 1.0000x reference)
//
#include <hip/hip_runtime.h>
#include <stdint.h>

typedef int   v4i __attribute__((ext_vector_type(4)));
typedef float v4f __attribute__((ext_vector_type(4)));

// LDS map:
//   [0, 2*13824)  act slots: hi at l*2304 + b*144 + k, lo plane at +6912
//   BIAS_OFF      fp32 pre-scaled bias [l][R,Z,NX,NH][h] (6144 B)
//   FC_OFF        fc i8 frags (2 KB)
//   WLDS_A        A-wave LDS weight frags: 4 waves * 20 frags * 1KB
//   WLDS_B        B-wave LDS weight frags: 4 waves * 4 frags * 1KB
#define SLOT_SZ  13824
#define LO_OFF   6912
#define BIAS_OFF (2*SLOT_SZ)            // 27648
#define FC_OFF   (BIAS_OFF + 6144)      // 33792
#define WLDS_A   (FC_OFF + 2048)        // 35840
#define WLDS_B   (WLDS_A + 81920)       // 117760
#define SMEM_SZ  (WLDS_B + 16384)       // 134144  (<=160K, 1 WG/CU)

#define QW   1436.84056f                // 127/s, s = 1/sqrt(128)
#define L2E  1.44269504f
#define CMf  (1.0f/(QW*2032.0f))        // act V-scale 2032 = 15.875*128
#define CRmf (-(L2E)*CMf)
#define CXmf (2.0f*(L2E)*CMf)

#define MFMA(A,B,C) __builtin_amdgcn_mfma_i32_16x16x64_i8(A, B, C, 0, 0, 0)

// i8 weight image (unchanged): blk = l*12 + o*2 + kh; o: 0 Rx,1 Rh,2 Zx,3 Zh,4 Nx,5 Nh.
// lane(g=lane&15, q=lane>>4) holds W[row g][k = kh*64 + q*16 + j], j=0..15.
__global__ void prep_weights(const float* __restrict__ Wih,
                             const float* __restrict__ Whh,
                             int8_t* __restrict__ img) {
  int bid = blockIdx.x, lane = threadIdx.x;          // 288 blocks x 64
  int w = bid / 36, blk = bid % 36;
  int l = blk / 12, rem = blk % 12, o = rem >> 1, kh = rem & 1;
  const float* M = (o & 1) ? Whh : Wih;
  int row = (o >> 1) * 128 + w * 16 + (lane & 15);
  int k0 = kh * 64 + (lane >> 4) * 16;
  const float* src = M + l * 49152 + row * 128 + k0;
  int words[4];
  #pragma unroll
  for (int j4 = 0; j4 < 4; ++j4) {
    unsigned wd = 0;
    #pragma unroll
    for (int j = 0; j < 4; ++j) {
      int q = (int)rintf(src[j4 * 4 + j] * QW);
      wd |= ((unsigned)(q & 255)) << (8 * j);
    }
    words[j4] = (int)wd;
  }
  *(v4i*)(img + (((long)bid) * 64 + lane) * 16) = *(const v4i*)words;
}

__global__ __launch_bounds__(512, 2)
void gru_main(const float* __restrict__ hiddens, const float* __restrict__ bih,
              const float* __restrict__ bhh, const float* __restrict__ fcw,
              const float* __restrict__ fcb, const int8_t* __restrict__ img,
              float* __restrict__ out) {
  extern __shared__ char smem[];
  const int tid = threadIdx.x, wg = blockIdx.x;
  const int lane = tid & 63, w = tid >> 6, col = lane & 15, q = lane >> 4;
  const bool isA = (w < 4);
  const int g = isA ? w : (w - 4);      // group-local wave index

#define LDIMG(BLK) (*(const v4i*)(img + (((long)(BLK)) * 64 + lane) * 16))
#define LDSA(i,u)  (*(const v4i*)(smem + WLDS_A + g*20480 + ((i)*10+(u))*1024 + lane*16))
#define LDSB(i,u)  (*(const v4i*)(smem + WLDS_B + g*4096  + ((i)*2 +(u))*1024 + lane*16))

  // ---- weight fragments ----
  // A regs per tile: k0..9 = l0 {Rx2,Rh2,Zx2,Zh2,Nx2}; k10,11 = l2 Rh; k12,13 = l2 Zx
  // A LDS  per tile: u0,1 l0Nh; u2,3 l2Rx; u4,5 l2Zh; u6,7 l2Nx; u8,9 l2Nh
  // B regs per tile: k0..9 = l1 {Rx2,Rh2,Zx2,Zh2,Nx2}; B LDS: u0,1 l1Nh
  v4i wra[2][14]; v4i wrb[2][10];
  if (isA) {
    #pragma unroll
    for (int i = 0; i < 2; ++i) {
      const int tw = (2 * g + i) * 36;
      #pragma unroll
      for (int k = 0; k < 10; ++k) wra[i][k] = LDIMG(tw + k);
      wra[i][10] = LDIMG(tw + 26); wra[i][11] = LDIMG(tw + 27);
      wra[i][12] = LDIMG(tw + 28); wra[i][13] = LDIMG(tw + 29);
      const int blks[10] = {10, 11, 24, 25, 30, 31, 32, 33, 34, 35};
      #pragma unroll
      for (int u = 0; u < 10; ++u)
        *(v4i*)(smem + WLDS_A + g*20480 + (i*10+u)*1024 + lane*16) = LDIMG(tw + blks[u]);
    }
  } else {
    #pragma unroll
    for (int i = 0; i < 2; ++i) {
      const int tw = (2 * g + i) * 36;
      #pragma unroll
      for (int k = 0; k < 10; ++k) wrb[i][k] = LDIMG(tw + 12 + k);
      #pragma unroll
      for (int u = 0; u < 2; ++u)
        *(v4i*)(smem + WLDS_B + g*4096 + (i*2+u)*1024 + lane*16) = LDIMG(tw + 22 + u);
    }
  }
  // ---- fc i8 frags to LDS ----
  if (tid < 128) {
    int kh = tid >> 6, ln = tid & 63, c2 = ln & 15, q2 = ln >> 4;
    int words[4] = {0, 0, 0, 0};
    if (c2 < 2) {
      const float* src = fcw + c2 * 128 + kh * 64 + q2 * 16;
      #pragma unroll
      for (int j4 = 0; j4 < 4; ++j4) {
        unsigned wd = 0;
        #pragma unroll
        for (int j = 0; j < 4; ++j) {
          int qv = (int)rintf(src[j4 * 4 + j] * QW);
          wd |= ((unsigned)(qv & 255)) << (8 * j);
        }
        words[j4] = (int)wd;
      }
    }
    *(v4i*)(smem + FC_OFF + kh * 1024 + ln * 16) = *(const v4i*)words;
  }
  // ---- pre-scaled bias table ----
  for (int i = tid; i < 1536; i += 512) {
    int l = i >> 9, type = (i >> 7) & 3, h = i & 127;
    float bv;
    if      (type == 0) bv = -L2E * (bih[l * 384 + h]       + bhh[l * 384 + h]);
    else if (type == 1) bv = -L2E * (bih[l * 384 + 128 + h] + bhh[l * 384 + 128 + h]);
    else if (type == 2) bv = 2.0f * L2E * bih[l * 384 + 256 + h];
    else                bv = 2.0f * L2E * bhh[l * 384 + 256 + h];
    *(float*)(smem + BIAS_OFF + i * 4) = bv;
  }
  // ---- act slot0 init (base-128 hi/lo encode) ----
  for (int i = tid; i < 6144; i += 512) {
    int l = i >> 11, b = (i >> 7) & 15, h = i & 127;
    float v = hiddens[((long)(wg * 16 + b)) * 384 + l * 128 + h];
    int V = (int)rintf(v * 2032.f);
    int hb = (V + 64) >> 7, lb = V - (hb << 7);
    *(int8_t*)(smem + l * 2304 + b * 144 + h)          = (int8_t)hb;
    *(int8_t*)(smem + l * 2304 + b * 144 + h + LO_OFF) = (int8_t)lb;
  }
  // ---- h-state regs ----
  v4f hstA[2][2]; v4f hstB[2];
  if (isA) {
    #pragma unroll
    for (int il = 0; il < 2; ++il)
      #pragma unroll
      for (int i = 0; i < 2; ++i)
        #pragma unroll
        for (int r = 0; r < 4; ++r)
          hstA[il][i][r] = hiddens[((long)(wg*16+col))*384 + (il*2)*128 + (2*g+i)*16 + q*4 + r];
  } else {
    #pragma unroll
    for (int i = 0; i < 2; ++i)
      #pragma unroll
      for (int r = 0; r < 4; ++r)
        hstB[i][r] = hiddens[((long)(wg*16+col))*384 + 128 + (2*g+i)*16 + q*4 + r];
  }
  const float fcb0 = fcb[0], fcb1 = fcb[1];
  __syncthreads();

  v4i fcr0 = {0,0,0,0}, fcr1 = {0,0,0,0};
  if (w == 4) {
    fcr0 = *(const v4i*)(smem + FC_OFF + lane * 16);
    fcr1 = *(const v4i*)(smem + FC_OFF + 1024 + lane * 16);
  }

  const char* fragb = smem + col * 144 + q * 16;

  auto lda = [&](const char* ap, v4i* f) {
    f[0] = *(const v4i*)ap;            f[1] = *(const v4i*)(ap + 64);
    f[2] = *(const v4i*)(ap + LO_OFF); f[3] = *(const v4i*)(ap + LO_OFF + 64);
  };
  auto mm2 = [&](v4i& aH, v4i& aL, v4i w0, v4i w1, const v4i* p) {
    aH = MFMA(w0, p[0], aH); aH = MFMA(w1, p[1], aH);
    aL = MFMA(w0, p[2], aL); aL = MFMA(w1, p[3], aL);
  };
  auto ewt = [&](int L, int tile, v4i Rh, v4i Rl, v4i Zh, v4i Zl,
                 v4i Xh, v4i Xl, v4i Hh, v4i Hl, v4f& hst, int sn) {
    const char* bb = smem + BIAS_OFF + (tile * 16 + q * 4) * 4;
    v4f bR = *(const v4f*)(bb + (L * 4 + 0) * 512);
    v4f bZ = *(const v4f*)(bb + (L * 4 + 1) * 512);
    v4f bX = *(const v4f*)(bb + (L * 4 + 2) * 512);
    v4f bH = *(const v4f*)(bb + (L * 4 + 3) * 512);
    unsigned hiw = 0, low = 0;
    #pragma unroll
    for (int r = 0; r < 4; ++r) {
      float gR = fmaf(CRmf, (float)((Rh[r] << 7) + Rl[r]), bR[r]);
      float gZ = fmaf(CRmf, (float)((Zh[r] << 7) + Zl[r]), bZ[r]);
      float gX = fmaf(CXmf, (float)((Xh[r] << 7) + Xl[r]), bX[r]);
      float gH = fmaf(CXmf, (float)((Hh[r] << 7) + Hl[r]), bH[r]);
      float rg = __builtin_amdgcn_rcpf(1.f + __builtin_amdgcn_exp2f(gR));
      float zg = __builtin_amdgcn_rcpf(1.f + __builtin_amdgcn_exp2f(gZ));
      float u  = __builtin_amdgcn_rcpf(1.f + __builtin_amdgcn_exp2f(fmaf(rg, gH, gX)));
      float ng = fmaf(-2.f, u, 1.f);
      float hn = fmaf(zg, hst[r] - ng, ng);
      hst[r] = hn;
      int V = (int)rintf(hn * 2032.f);
      int hb = (V + 64) >> 7, lb = V - (hb << 7);
      hiw |= ((unsigned)(hb & 255)) << (8 * r);
      low |= ((unsigned)(lb & 255)) << (8 * r);
    }
    char* wp = smem + sn + L * 2304 + col * 144 + tile * 16 + q * 4;
    *(unsigned*)wp = hiw;
    *(unsigned*)(wp + LO_OFF) = low;
  };

  v4i pRh[2], pRl[2], pZh[2], pZl[2], pHh[2], pHl[2];   // A: l2 persist; B: l1 persist
  const v4i Z4 = {0, 0, 0, 0};

  #pragma unroll 1
  for (int t = 0; t < 256; ++t) {
    const int so = (t & 1) * SLOT_SZ;
    const int sn = SLOT_SZ - so;
    // ================= P0: A: layer0 full + EW  |  B(w4): FC(t-1) =================
    if (isA) {
      v4i ha[4], xa[4];
      lda(fragb + so, ha);                       // l0 acts (old)
      if (t > 0) lda(fragb + so + 2 * 2304, xa); // l2 acts (old) = x0
      #pragma unroll
      for (int i = 0; i < 2; ++i) {
        v4i Rh = Z4, Rl = Z4, Zh = Z4, Zl = Z4, Xh = Z4, Xl = Z4, Hh = Z4, Hl = Z4;
        mm2(Rh, Rl, wra[i][2], wra[i][3], ha);
        mm2(Zh, Zl, wra[i][6], wra[i][7], ha);
        mm2(Hh, Hl, LDSA(i, 0), LDSA(i, 1), ha);
        if (t > 0) {
          mm2(Rh, Rl, wra[i][0], wra[i][1], xa);
          mm2(Zh, Zl, wra[i][4], wra[i][5], xa);
          mm2(Xh, Xl, wra[i][8], wra[i][9], xa);
        }
        ewt(0, 2 * g + i, Rh, Rl, Zh, Zl, Xh, Xl, Hh, Hl, hstA[0][i], sn);
      }
    } else if (w == 4 && t > 0) {
      v4i fa[4];
      lda(fragb + so + 2 * 2304, fa);
      v4i dh = Z4, dl = Z4;
      dh = MFMA(fcr0, fa[0], dh); dh = MFMA(fcr1, fa[1], dh);
      dl = MFMA(fcr0, fa[2], dl); dl = MFMA(fcr1, fa[3], dl);
      if (q == 0) {
        float2 o2;
        o2.x = fcb0 + CMf * (float)((dh[0] << 7) + dl[0]);
        o2.y = fcb1 + CMf * (float)((dh[1] << 7) + dl[1]);
        *(float2*)(out + (((long)(wg * 16 + col)) * 256 + (t - 1)) * 2) = o2;
      }
    }
    __syncthreads();
    // ================= P1: B: layer1 x + EW  |  A: layer2 h-side =================
    if (isA) {
      v4i ha[4];
      lda(fragb + so + 2 * 2304, ha);            // l2 acts (old)
      #pragma unroll
      for (int i = 0; i < 2; ++i) {
        pRh[i] = Z4; pRl[i] = Z4; pZh[i] = Z4; pZl[i] = Z4; pHh[i] = Z4; pHl[i] = Z4;
        mm2(pRh[i], pRl[i], wra[i][10], wra[i][11], ha);  // l2 Rh
        mm2(pZh[i], pZl[i], LDSA(i, 4), LDSA(i, 5), ha);  // l2 Zh
        mm2(pHh[i], pHl[i], LDSA(i, 8), LDSA(i, 9), ha);  // l2 Nh
      }
    } else {
      v4i xa[4], ha[4];
      lda(fragb + sn, xa);                       // l0 acts (new)
      if (t == 0) lda(fragb + 1 * 2304, ha);     // l1 acts (init, so=0)
      #pragma unroll
      for (int i = 0; i < 2; ++i) {
        if (t == 0) {
          pRh[i] = Z4; pRl[i] = Z4; pZh[i] = Z4; pZl[i] = Z4; pHh[i] = Z4; pHl[i] = Z4;
          mm2(pRh[i], pRl[i], wrb[i][2], wrb[i][3], ha);
          mm2(pZh[i], pZl[i], wrb[i][6], wrb[i][7], ha);
          mm2(pHh[i], pHl[i], LDSB(i, 0), LDSB(i, 1), ha);
        }
        v4i Xh = Z4, Xl = Z4;
        mm2(pRh[i], pRl[i], wrb[i][0], wrb[i][1], xa);
        mm2(pZh[i], pZl[i], wrb[i][4], wrb[i][5], xa);
        mm2(Xh, Xl, wrb[i][8], wrb[i][9], xa);
        ewt(1, 2 * g + i, pRh[i], pRl[i], pZh[i], pZl[i], Xh, Xl, pHh[i], pHl[i],
            hstB[i], sn);
      }
    }
    __syncthreads();
    // ================= P2: A: layer2 x + EW  |  B: hoist l1-h(t+1) =================
    if (isA) {
      v4i xa[4];
      lda(fragb + sn + 1 * 2304, xa);            // l1 acts (new)
      #pragma unroll
      for (int i = 0; i < 2; ++i) {
        v4i Xh = Z4, Xl = Z4;
        mm2(pRh[i], pRl[i], LDSA(i, 2), LDSA(i, 3), xa);  // l2 Rx
        mm2(pZh[i], pZl[i], wra[i][12], wra[i][13], xa);  // l2 Zx
        mm2(Xh, Xl, LDSA(i, 6), LDSA(i, 7), xa);          // l2 Nx
        ewt(2, 2 * g + i, pRh[i], pRl[i], pZh[i], pZl[i], Xh, Xl, pHh[i], pHl[i],
            hstA[1][i], sn);
      }
    } else {
      v4i ha[4];
      lda(fragb + sn + 1 * 2304, ha);            // l1 acts (new) = next step h
      #pragma unroll
      for (int i = 0; i < 2; ++i) {
        pRh[i] = Z4; pRl[i] = Z4; pZh[i] = Z4; pZl[i] = Z4; pHh[i] = Z4; pHl[i] = Z4;
        mm2(pRh[i], pRl[i], wrb[i][2], wrb[i][3], ha);
        mm2(pZh[i], pZl[i], wrb[i][6], wrb[i][7], ha);
        mm2(pHh[i], pHl[i], LDSB(i, 0), LDSB(i, 1), ha);
      }
    }
    __syncthreads();
  }

  // ---- final FC for t=255 (l2 acts in slot 0) ----
  if (w == 4) {
    v4i fa[4];
    lda(fragb + 2 * 2304, fa);
    v4i dh = Z4, dl = Z4;
    dh = MFMA(fcr0, fa[0], dh); dh = MFMA(fcr1, fa[1], dh);
    dl = MFMA(fcr0, fa[2], dl); dl = MFMA(fcr1, fa[3], dl);
    if (q == 0) {
      float2 o2;
      o2.x = fcb0 + CMf * (float)((dh[0] << 7) + dl[0]);
      o2.y = fcb1 + CMf * (float)((dh[1] << 7) + dl[1]);
      *(float2*)(out + (((long)(wg * 16 + col)) * 256 + 255) * 2) = o2;
    }
  }
}

extern "C" void kernel_launch(void* const* d_in, const int* in_sizes, int n_in,
                              void* d_out, int out_size, void* d_ws, size_t ws_size,
                              hipStream_t stream) {
  (void)in_sizes; (void)n_in; (void)out_size; (void)ws_size;
  const float* hiddens = (const float*)d_in[0];
  const float* Wih     = (const float*)d_in[1];
  const float* Whh     = (const float*)d_in[2];
  const float* bih     = (const float*)d_in[3];
  const float* bhh     = (const float*)d_in[4];
  const float* fcw     = (const float*)d_in[5];
  const float* fcb     = (const float*)d_in[6];
  int8_t* img = (int8_t*)d_ws;   // 288 KB weight image
  float* out = (float*)d_out;

  hipFuncSetAttribute(reinterpret_cast<const void*>(gru_main),
                      hipFuncAttributeMaxDynamicSharedMemorySize, SMEM_SZ);

  prep_weights<<<288, 64, 0, stream>>>(Wih, Whh, img);
  gru_main<<<64, 512, SMEM_SZ, stream>>>(hiddens, bih, bhh, fcw, fcb, img, out);
}

// Round 8
// 992.635 us; speedup vs baseline: 1.6990x; 1.6990x over previous
//
#include <hip/hip_runtime.h>
#include <stdint.h>

typedef int   v4i __attribute__((ext_vector_type(4)));
typedef float v4f __attribute__((ext_vector_type(4)));

// LDS map:
//   [0, 2*13824)  act slots: hi at l*2304 + b*144 + k, lo plane at +6912
//   BIAS_OFF      fp32 pre-scaled bias [l][R,Z,NX,NH][h] (6144 B)
//   FC_OFF        fc i8 frags (2 KB)
//   WLDS_A        l0 h-side weight frags: 8 tiles * 6 frags * 1KB = 48 KB
#define SLOT_SZ  13824
#define LO_OFF   6912
#define BIAS_OFF (2*SLOT_SZ)            // 27648
#define FC_OFF   (BIAS_OFF + 6144)      // 33792
#define WLDS_A   (FC_OFF + 2048)        // 35840
#define SMEM_SZ  (WLDS_A + 49152)       // 84992 (>64K: opt-in)

#define QW   1436.84056f                // 127/s, s = 1/sqrt(128)
#define L2E  1.44269504f
#define CMf  (1.0f/(QW*2032.0f))        // act V-scale 2032 = 15.875*128
#define CRmf (-(L2E)*CMf)
#define CXmf (2.0f*(L2E)*CMf)

#define MFMA(A,B,C) __builtin_amdgcn_mfma_i32_16x16x64_i8(A, B, C, 0, 0, 0)

// i8 weight image (unchanged): blk = l*12 + o*2 + kh; o: 0 Rx,1 Rh,2 Zx,3 Zh,4 Nx,5 Nh.
// lane(g=lane&15, q=lane>>4) holds W[row g][k = kh*64 + q*16 + j], j=0..15.
__global__ void prep_weights(const float* __restrict__ Wih,
                             const float* __restrict__ Whh,
                             int8_t* __restrict__ img) {
  int bid = blockIdx.x, lane = threadIdx.x;          // 288 blocks x 64
  int w = bid / 36, blk = bid % 36;
  int l = blk / 12, rem = blk % 12, o = rem >> 1, kh = rem & 1;
  const float* M = (o & 1) ? Whh : Wih;
  int row = (o >> 1) * 128 + w * 16 + (lane & 15);
  int k0 = kh * 64 + (lane >> 4) * 16;
  const float* src = M + l * 49152 + row * 128 + k0;
  int words[4];
  #pragma unroll
  for (int j4 = 0; j4 < 4; ++j4) {
    unsigned wd = 0;
    #pragma unroll
    for (int j = 0; j < 4; ++j) {
      int q = (int)rintf(src[j4 * 4 + j] * QW);
      wd |= ((unsigned)(q & 255)) << (8 * j);
    }
    words[j4] = (int)wd;
  }
  *(v4i*)(img + (((long)bid) * 64 + lane) * 16) = *(const v4i*)words;
}

__global__ __launch_bounds__(512, 2)
void gru_main(const float* __restrict__ hiddens, const float* __restrict__ bih,
              const float* __restrict__ bhh, const float* __restrict__ fcw,
              const float* __restrict__ fcb, const int8_t* __restrict__ img,
              float* __restrict__ out) {
  extern __shared__ char smem[];
  const int tid = threadIdx.x, wg = blockIdx.x;
  const int lane = tid & 63, w = tid >> 6, col = lane & 15, q = lane >> 4;
  const bool isA = (w < 4);
  const int g = isA ? w : (w - 4);

#define LDIMG(BLK) (*(const v4i*)(img + (((long)(BLK)) * 64 + lane) * 16))

  // ---- weight frags: SHARED arrays for both roles (union = 36 v4i, R6-proven) ----
  // A: wrX=l0-x, wrY=l2-x, wrZ=l2-h; l0-h -> LDS.   B: wrX=l1-x, wrY=l1-h.
  v4i wrX[2][6], wrY[2][6], wrZ[2][6];
  {
    const int XSEL[6] = {0, 1, 4, 5, 8, 9};
    const int HSEL[6] = {2, 3, 6, 7, 10, 11};
    #pragma unroll
    for (int i = 0; i < 2; ++i) {
      const int tw = (2 * g + i) * 36;
      if (isA) {
        #pragma unroll
        for (int u = 0; u < 6; ++u) {
          wrX[i][u] = LDIMG(tw + XSEL[u]);
          wrY[i][u] = LDIMG(tw + 24 + XSEL[u]);
          wrZ[i][u] = LDIMG(tw + 24 + HSEL[u]);
          *(v4i*)(smem + WLDS_A + (2 * g + i) * 6144 + u * 1024 + lane * 16) =
              LDIMG(tw + HSEL[u]);
        }
      } else {
        #pragma unroll
        for (int u = 0; u < 6; ++u) {
          wrX[i][u] = LDIMG(tw + 12 + XSEL[u]);
          wrY[i][u] = LDIMG(tw + 12 + HSEL[u]);
        }
      }
    }
  }
  // ---- fc i8 frags to LDS ----
  if (tid < 128) {
    int kh = tid >> 6, ln = tid & 63, c2 = ln & 15, q2 = ln >> 4;
    int words[4] = {0, 0, 0, 0};
    if (c2 < 2) {
      const float* src = fcw + c2 * 128 + kh * 64 + q2 * 16;
      #pragma unroll
      for (int j4 = 0; j4 < 4; ++j4) {
        unsigned wd = 0;
        #pragma unroll
        for (int j = 0; j < 4; ++j) {
          int qv = (int)rintf(src[j4 * 4 + j] * QW);
          wd |= ((unsigned)(qv & 255)) << (8 * j);
        }
        words[j4] = (int)wd;
      }
    }
    *(v4i*)(smem + FC_OFF + kh * 1024 + ln * 16) = *(const v4i*)words;
  }
  // ---- pre-scaled bias table ----
  for (int i = tid; i < 1536; i += 512) {
    int l = i >> 9, type = (i >> 7) & 3, h = i & 127;
    float bv;
    if      (type == 0) bv = -L2E * (bih[l * 384 + h]       + bhh[l * 384 + h]);
    else if (type == 1) bv = -L2E * (bih[l * 384 + 128 + h] + bhh[l * 384 + 128 + h]);
    else if (type == 2) bv = 2.0f * L2E * bih[l * 384 + 256 + h];
    else                bv = 2.0f * L2E * bhh[l * 384 + 256 + h];
    *(float*)(smem + BIAS_OFF + i * 4) = bv;
  }
  // ---- act slot0 init (base-128 hi/lo encode) ----
  for (int i = tid; i < 6144; i += 512) {
    int l = i >> 11, b = (i >> 7) & 15, h = i & 127;
    float v = hiddens[((long)(wg * 16 + b)) * 384 + l * 128 + h];
    int V = (int)rintf(v * 2032.f);
    int hb = (V + 64) >> 7, lb = V - (hb << 7);
    *(int8_t*)(smem + l * 2304 + b * 144 + h)          = (int8_t)hb;
    *(int8_t*)(smem + l * 2304 + b * 144 + h + LO_OFF) = (int8_t)lb;
  }
  // ---- h-state regs: A: [0]=l0,[1]=l2; B: [0]=l1 ----
  v4f hst[2][2];
  #pragma unroll
  for (int i = 0; i < 2; ++i)
    #pragma unroll
    for (int r = 0; r < 4; ++r) {
      int hrow = (2 * g + i) * 16 + q * 4 + r;
      if (isA) {
        hst[0][i][r] = hiddens[((long)(wg * 16 + col)) * 384 + 0 * 128 + hrow];
        hst[1][i][r] = hiddens[((long)(wg * 16 + col)) * 384 + 2 * 128 + hrow];
      } else {
        hst[0][i][r] = hiddens[((long)(wg * 16 + col)) * 384 + 1 * 128 + hrow];
      }
    }
  const float fcb0 = fcb[0], fcb1 = fcb[1];
  __syncthreads();

  v4i fcr0 = {0,0,0,0}, fcr1 = {0,0,0,0};
  if (w == 4) {
    fcr0 = *(const v4i*)(smem + FC_OFF + lane * 16);
    fcr1 = *(const v4i*)(smem + FC_OFF + 1024 + lane * 16);
  }

  const char* fragb = smem + col * 144 + q * 16;
  const v4i Z4 = {0, 0, 0, 0};

  auto lda = [&](const char* ap, v4i* f) {
    f[0] = *(const v4i*)ap;            f[1] = *(const v4i*)(ap + 64);
    f[2] = *(const v4i*)(ap + LO_OFF); f[3] = *(const v4i*)(ap + LO_OFF + 64);
  };
  auto ewt = [&](int L, int T, v4i Rh, v4i Rl, v4i Zh, v4i Zl,
                 v4i Xh, v4i Xl, v4i Hh, v4i Hl, v4f& h4, int sn) {
    const char* bb = smem + BIAS_OFF + (T * 16 + q * 4) * 4;
    v4f bR = *(const v4f*)(bb + (L * 4 + 0) * 512);
    v4f bZ = *(const v4f*)(bb + (L * 4 + 1) * 512);
    v4f bX = *(const v4f*)(bb + (L * 4 + 2) * 512);
    v4f bH = *(const v4f*)(bb + (L * 4 + 3) * 512);
    unsigned hiw = 0, low = 0;
    #pragma unroll
    for (int r = 0; r < 4; ++r) {
      float gR = fmaf(CRmf, (float)((Rh[r] << 7) + Rl[r]), bR[r]);
      float gZ = fmaf(CRmf, (float)((Zh[r] << 7) + Zl[r]), bZ[r]);
      float gX = fmaf(CXmf, (float)((Xh[r] << 7) + Xl[r]), bX[r]);
      float gH = fmaf(CXmf, (float)((Hh[r] << 7) + Hl[r]), bH[r]);
      float rg = __builtin_amdgcn_rcpf(1.f + __builtin_amdgcn_exp2f(gR));
      float zg = __builtin_amdgcn_rcpf(1.f + __builtin_amdgcn_exp2f(gZ));
      float u  = __builtin_amdgcn_rcpf(1.f + __builtin_amdgcn_exp2f(fmaf(rg, gH, gX)));
      float ng = fmaf(-2.f, u, 1.f);
      float hn = fmaf(zg, h4[r] - ng, ng);
      h4[r] = hn;
      float fq = fmaf(hn, 2032.f, 12582912.f);          // RNE magic round
      int V = __float_as_int(fq) - 0x4B400000;
      int hb = (V + 64) >> 7, lb = V - (hb << 7);
      hiw |= ((unsigned)(hb & 255)) << (8 * r);
      low |= ((unsigned)(lb & 255)) << (8 * r);
    }
    char* wp = smem + sn + L * 2304 + col * 144 + T * 16 + q * 4;
    *(unsigned*)wp = hiw;
    *(unsigned*)(wp + LO_OFF) = low;
  };

  // persists: shared by roles; born and die within one t-iteration
  v4i psR[2][2], psZ[2][2], psH[2][2];
  v4i xc[4];   // A: cached l2-old acts (P0->P1); w4: FC act frags

  #pragma unroll 1
  for (int t = 0; t < 256; ++t) {
    const int so = (t & 1) * SLOT_SZ;
    const int sn = SLOT_SZ - so;
    // ===== P0: A: layer0 full + EW0  |  B: l1-h persists (+w4 FC) =====
    if (isA) {
      v4i ha[4];
      lda(fragb + so, ha);                         // l0-old
      if (t > 0) lda(fragb + so + 2 * 2304, xc);   // l2-old (x0), cached for P1
      #pragma unroll
      for (int i = 0; i < 2; ++i) {
        v4i wl[6];
        #pragma unroll
        for (int u = 0; u < 6; ++u)
          wl[u] = *(const v4i*)(smem + WLDS_A + (2 * g + i) * 6144 + u * 1024 + lane * 16);
        v4i Rh = Z4, Rl = Z4, Zh = Z4, Zl = Z4, Xh = Z4, Xl = Z4, Hh = Z4, Hl = Z4;
        Rh = MFMA(wl[0], ha[0], Rh); Rh = MFMA(wl[1], ha[1], Rh);
        Rl = MFMA(wl[0], ha[2], Rl); Rl = MFMA(wl[1], ha[3], Rl);
        Zh = MFMA(wl[2], ha[0], Zh); Zh = MFMA(wl[3], ha[1], Zh);
        Zl = MFMA(wl[2], ha[2], Zl); Zl = MFMA(wl[3], ha[3], Zl);
        Hh = MFMA(wl[4], ha[0], Hh); Hh = MFMA(wl[5], ha[1], Hh);
        Hl = MFMA(wl[4], ha[2], Hl); Hl = MFMA(wl[5], ha[3], Hl);
        if (t > 0) {
          Rh = MFMA(wrX[i][0], xc[0], Rh); Rh = MFMA(wrX[i][1], xc[1], Rh);
          Rl = MFMA(wrX[i][0], xc[2], Rl); Rl = MFMA(wrX[i][1], xc[3], Rl);
          Zh = MFMA(wrX[i][2], xc[0], Zh); Zh = MFMA(wrX[i][3], xc[1], Zh);
          Zl = MFMA(wrX[i][2], xc[2], Zl); Zl = MFMA(wrX[i][3], xc[3], Zl);
          Xh = MFMA(wrX[i][4], xc[0], Xh); Xh = MFMA(wrX[i][5], xc[1], Xh);
          Xl = MFMA(wrX[i][4], xc[2], Xl); Xl = MFMA(wrX[i][5], xc[3], Xl);
        }
        ewt(0, 2 * g + i, Rh, Rl, Zh, Zl, Xh, Xl, Hh, Hl, hst[0][i], sn);
      }
    } else {
      v4i hb4[4];
      lda(fragb + so + 1 * 2304, hb4);             // l1-old
      #pragma unroll
      for (int i = 0; i < 2; ++i) {
        psR[i][0] = Z4; psR[i][1] = Z4; psZ[i][0] = Z4; psZ[i][1] = Z4;
        psH[i][0] = Z4; psH[i][1] = Z4;
        psR[i][0] = MFMA(wrY[i][0], hb4[0], psR[i][0]);
        psR[i][0] = MFMA(wrY[i][1], hb4[1], psR[i][0]);
        psR[i][1] = MFMA(wrY[i][0], hb4[2], psR[i][1]);
        psR[i][1] = MFMA(wrY[i][1], hb4[3], psR[i][1]);
        psZ[i][0] = MFMA(wrY[i][2], hb4[0], psZ[i][0]);
        psZ[i][0] = MFMA(wrY[i][3], hb4[1], psZ[i][0]);
        psZ[i][1] = MFMA(wrY[i][2], hb4[2], psZ[i][1]);
        psZ[i][1] = MFMA(wrY[i][3], hb4[3], psZ[i][1]);
        psH[i][0] = MFMA(wrY[i][4], hb4[0], psH[i][0]);
        psH[i][0] = MFMA(wrY[i][5], hb4[1], psH[i][0]);
        psH[i][1] = MFMA(wrY[i][4], hb4[2], psH[i][1]);
        psH[i][1] = MFMA(wrY[i][5], hb4[3], psH[i][1]);
      }
      if (w == 4 && t > 0) {
        lda(fragb + so + 2 * 2304, xc);            // l2-old for FC(t-1)
        v4i dh = Z4, dl = Z4;
        dh = MFMA(fcr0, xc[0], dh); dh = MFMA(fcr1, xc[1], dh);
        dl = MFMA(fcr0, xc[2], dl); dl = MFMA(fcr1, xc[3], dl);
        if (q == 0) {
          float2 o2;
          o2.x = fcb0 + CMf * (float)((dh[0] << 7) + dl[0]);
          o2.y = fcb1 + CMf * (float)((dh[1] << 7) + dl[1]);
          *(float2*)(out + (((long)(wg * 16 + col)) * 256 + (t - 1)) * 2) = o2;
        }
      }
    }
    __syncthreads();
    // ===== P1: B: l1-x + EW1  |  A: l2-h persists =====
    if (isA) {
      if (t == 0) lda(fragb + so + 2 * 2304, xc);  // l2-old (not cached at t=0)
      #pragma unroll
      for (int i = 0; i < 2; ++i) {
        psR[i][0] = Z4; psR[i][1] = Z4; psZ[i][0] = Z4; psZ[i][1] = Z4;
        psH[i][0] = Z4; psH[i][1] = Z4;
        psR[i][0] = MFMA(wrZ[i][0], xc[0], psR[i][0]);
        psR[i][0] = MFMA(wrZ[i][1], xc[1], psR[i][0]);
        psR[i][1] = MFMA(wrZ[i][0], xc[2], psR[i][1]);
        psR[i][1] = MFMA(wrZ[i][1], xc[3], psR[i][1]);
        psZ[i][0] = MFMA(wrZ[i][2], xc[0], psZ[i][0]);
        psZ[i][0] = MFMA(wrZ[i][3], xc[1], psZ[i][0]);
        psZ[i][1] = MFMA(wrZ[i][2], xc[2], psZ[i][1]);
        psZ[i][1] = MFMA(wrZ[i][3], xc[3], psZ[i][1]);
        psH[i][0] = MFMA(wrZ[i][4], xc[0], psH[i][0]);
        psH[i][0] = MFMA(wrZ[i][5], xc[1], psH[i][0]);
        psH[i][1] = MFMA(wrZ[i][4], xc[2], psH[i][1]);
        psH[i][1] = MFMA(wrZ[i][5], xc[3], psH[i][1]);
      }
    } else {
      v4i xb[4];
      lda(fragb + sn, xb);                         // l0-new
      #pragma unroll
      for (int i = 0; i < 2; ++i) {
        v4i Xh = Z4, Xl = Z4;
        psR[i][0] = MFMA(wrX[i][0], xb[0], psR[i][0]);
        psR[i][0] = MFMA(wrX[i][1], xb[1], psR[i][0]);
        psR[i][1] = MFMA(wrX[i][0], xb[2], psR[i][1]);
        psR[i][1] = MFMA(wrX[i][1], xb[3], psR[i][1]);
        psZ[i][0] = MFMA(wrX[i][2], xb[0], psZ[i][0]);
        psZ[i][0] = MFMA(wrX[i][3], xb[1], psZ[i][0]);
        psZ[i][1] = MFMA(wrX[i][2], xb[2], psZ[i][1]);
        psZ[i][1] = MFMA(wrX[i][3], xb[3], psZ[i][1]);
        Xh = MFMA(wrX[i][4], xb[0], Xh); Xh = MFMA(wrX[i][5], xb[1], Xh);
        Xl = MFMA(wrX[i][4], xb[2], Xl); Xl = MFMA(wrX[i][5], xb[3], Xl);
        ewt(1, 2 * g + i, psR[i][0], psR[i][1], psZ[i][0], psZ[i][1],
            Xh, Xl, psH[i][0], psH[i][1], hst[0][i], sn);
      }
    }
    __syncthreads();
    // ===== P2: A: l2-x + EW2  |  B: idle =====
    if (isA) {
      v4i xb[4];
      lda(fragb + sn + 1 * 2304, xb);              // l1-new
      #pragma unroll
      for (int i = 0; i < 2; ++i) {
        v4i Xh = Z4, Xl = Z4;
        psR[i][0] = MFMA(wrY[i][0], xb[0], psR[i][0]);
        psR[i][0] = MFMA(wrY[i][1], xb[1], psR[i][0]);
        psR[i][1] = MFMA(wrY[i][0], xb[2], psR[i][1]);
        psR[i][1] = MFMA(wrY[i][1], xb[3], psR[i][1]);
        psZ[i][0] = MFMA(wrY[i][2], xb[0], psZ[i][0]);
        psZ[i][0] = MFMA(wrY[i][3], xb[1], psZ[i][0]);
        psZ[i][1] = MFMA(wrY[i][2], xb[2], psZ[i][1]);
        psZ[i][1] = MFMA(wrY[i][3], xb[3], psZ[i][1]);
        Xh = MFMA(wrY[i][4], xb[0], Xh); Xh = MFMA(wrY[i][5], xb[1], Xh);
        Xl = MFMA(wrY[i][4], xb[2], Xl); Xl = MFMA(wrY[i][5], xb[3], Xl);
        ewt(2, 2 * g + i, psR[i][0], psR[i][1], psZ[i][0], psZ[i][1],
            Xh, Xl, psH[i][0], psH[i][1], hst[1][i], sn);
      }
    }
    __syncthreads();
  }

  // ---- final FC for t=255 (l2 acts in slot 0) ----
  if (w == 4) {
    lda(fragb + 2 * 2304, xc);
    v4i dh = Z4, dl = Z4;
    dh = MFMA(fcr0, xc[0], dh); dh = MFMA(fcr1, xc[1], dh);
    dl = MFMA(fcr0, xc[2], dl); dl = MFMA(fcr1, xc[3], dl);
    if (q == 0) {
      float2 o2;
      o2.x = fcb0 + CMf * (float)((dh[0] << 7) + dl[0]);
      o2.y = fcb1 + CMf * (float)((dh[1] << 7) + dl[1]);
      *(float2*)(out + (((long)(wg * 16 + col)) * 256 + 255) * 2) = o2;
    }
  }
}

extern "C" void kernel_launch(void* const* d_in, const int* in_sizes, int n_in,
                              void* d_out, int out_size, void* d_ws, size_t ws_size,
                              hipStream_t stream) {
  (void)in_sizes; (void)n_in; (void)out_size; (void)ws_size;
  const float* hiddens = (const float*)d_in[0];
  const float* Wih     = (const float*)d_in[1];
  const float* Whh     = (const float*)d_in[2];
  const float* bih     = (const float*)d_in[3];
  const float* bhh     = (const float*)d_in[4];
  const float* fcw     = (const float*)d_in[5];
  const float* fcb     = (const float*)d_in[6];
  int8_t* img = (int8_t*)d_ws;   // 288 KB weight image
  float* out = (float*)d_out;

  hipFuncSetAttribute(reinterpret_cast<const void*>(gru_main),
                      hipFuncAttributeMaxDynamicSharedMemorySize, SMEM_SZ);

  prep_weights<<<288, 64, 0, stream>>>(Wih, Whh, img);
  gru_main<<<64, 512, SMEM_SZ, stream>>>(hiddens, bih, bhh, fcw, fcb, img, out);
}